// Round 5
// baseline (538.600 us; speedup 1.0000x reference)
//
#include <hip/hip_runtime.h>

// SensorAutoEncoder: 10-layer MLP over 1M rows of 43 floats, fused persistent
// kernel. fp16 MFMA (16x16x32) + fp32 accumulate. R5: inter-layer hidden state
// stays in registers with NO cross-lane exchange — the packed D dwords are
// reinterpreted directly as the next layer's B-fragment, and the induced
// k-permutation F is folded into the weight staging of layers 1..9.
//   B slot (c,g,j), d=j>>1, o=j&1:
//     c==0        -> F = 16*(d>>1) + 4g + 2*(d&1) + o
//     c==1, d<2   -> F = 32 + 4g + 2d + o
//     c==1, d>=2  -> zero pad
// LDS holds only the fp16 (permuted) W^T tiles.

typedef __fp16 pk16x2 __attribute__((ext_vector_type(2)));   // cvt_pkrtz type
typedef _Float16 f16x8 __attribute__((ext_vector_type(8)));
typedef float f32x4 __attribute__((ext_vector_type(4)));

#define TPB 1024
#define NBLK 256
#define ITERS 8
#define NROWS 1048576
#define NCOL 43
#define ROWB 172u                       // bytes per x row (43 f32)
#define XBYTES (NROWS * (size_t)ROWB)   // 180,355,072 (< 2^31, u32 offsets ok)
#define WSTRIDE 72                      // halfwords per W^T row (144 B)
#define WSLOT (48 * WSTRIDE)            // halfwords per layer slot
#define SMEM_BYTES (10 * WSLOT * 2)     // 69120 B (weights only)

__device__ __forceinline__ float fast_tanh(float x) {
  // tanh(x) = 1 - 2/(1 + e^{2x});  e^{2x} = 2^{x * 2*log2(e)}
  float t = __builtin_amdgcn_exp2f(x * 2.8853900817779268f);
  float r = __builtin_amdgcn_rcpf(t + 1.0f);
  return __builtin_fmaf(-2.0f, r, 1.0f);
}

__device__ __forceinline__ unsigned pk2(float a, float b) {
  pk16x2 h = __builtin_amdgcn_cvt_pkrtz(a, b);
  return __builtin_bit_cast(unsigned, h);
}

struct Frags { f16x8 b[2][2]; };   // [s][c] B-fragments for next layer

// Epilogue: bias(optional)+tanh(optional)+bias-row forcing, pack to f16x2
// dwords, place directly into next layer's B-frag slots (no lane exchange).
template <int NT, bool DOTANH, int NLOUT, int KCN, bool ADDB>
__device__ __forceinline__ Frags epi_pack(f32x4 acc[3][2],
                                          const float* badd, int g) {
  Frags O;
#pragma unroll
  for (int s = 0; s < 2; ++s) {
    unsigned pk[3][2];
#pragma unroll
    for (int t = 0; t < NT; ++t) {
      float v[4];
#pragma unroll
      for (int r = 0; r < 4; ++r) {
        float u = acc[t][s][r];
        if (ADDB) u += badd[t * 4 + r];
        if (DOTANH) u = fast_tanh(u);
        if (t == (NLOUT >> 4)) {                 // bias-mult column -> 1.0
          int col = 16 * t + 4 * g + r;
          u = (col == NLOUT) ? 1.0f : u;
        }
        v[r] = u;
      }
      pk[t][0] = pk2(v[0], v[1]);
      pk[t][1] = pk2(v[2], v[3]);
    }
    union { unsigned d[4]; f16x8 v; } u0;
    u0.d[0] = pk[0][0]; u0.d[1] = pk[0][1];
    u0.d[2] = pk[1][0]; u0.d[3] = pk[1][1];
    O.b[s][0] = u0.v;
    if (KCN == 2) {
      union { unsigned d[4]; f16x8 v; } u1;
      u1.d[0] = pk[2][0]; u1.d[1] = pk[2][1];
      u1.d[2] = 0u;       u1.d[3] = 0u;
      O.b[s][1] = u1.v;
    } else {
      O.b[s][1] = O.b[s][0];   // unused by a KC=1 consumer
    }
  }
  return O;
}

// One layer: MFMA against LDS weights, epilogue+pack to next B-frags.
template <int NT, int KC, bool DOTANH, int NLOUT, int KCN, bool ADDB>
__device__ __forceinline__ Frags layer_fwd(const _Float16* __restrict__ Wl,
                                           const Frags& B, const float* badd,
                                           int g, int lr) {
  f32x4 acc[3][2];
#pragma unroll
  for (int t = 0; t < NT; ++t)
#pragma unroll
    for (int s = 0; s < 2; ++s) acc[t][s] = f32x4{0.f, 0.f, 0.f, 0.f};
#pragma unroll
  for (int c = 0; c < KC; ++c)
#pragma unroll
    for (int t = 0; t < NT; ++t) {
      f16x8 A = *(const f16x8*)(Wl + (16 * t + lr) * WSTRIDE + 8 * g + 32 * c);
#pragma unroll
      for (int s = 0; s < 2; ++s)
        acc[t][s] = __builtin_amdgcn_mfma_f32_16x16x32_f16(A, B.b[s][c],
                                                           acc[t][s], 0, 0, 0);
    }
  return epi_pack<NT, DOTANH, NLOUT, KCN, ADDB>(acc, badd, g);
}

extern "C" __global__ void __launch_bounds__(TPB, 1)
ae_kernel(const float* __restrict__ x,
          const float* __restrict__ W0, const float* __restrict__ B0,
          const float* __restrict__ W1, const float* __restrict__ B1,
          const float* __restrict__ W2, const float* __restrict__ B2,
          const float* __restrict__ W3, const float* __restrict__ B3,
          const float* __restrict__ W4, const float* __restrict__ B4,
          const float* __restrict__ W5, const float* __restrict__ B5,
          const float* __restrict__ W6, const float* __restrict__ B6,
          const float* __restrict__ W7, const float* __restrict__ B7,
          const float* __restrict__ W8, const float* __restrict__ B8,
          const float* __restrict__ W9, const float* __restrict__ B9,
          float* __restrict__ out) {
  extern __shared__ char smem[];
  _Float16* lw = (_Float16*)smem;

  const int tid = threadIdx.x;
  const int wave = tid >> 6;
  const int lane = tid & 63;
  const int g = lane >> 4;
  const int lr = lane & 15;

  // ---- stage weights as fp16 W^T, layers 1..9 with the k-permutation F ----
  {
    const float* Wp[10] = {W0, W1, W2, W3, W4, W5, W6, W7, W8, W9};
    const float* Bp[10] = {B0, B1, B2, B3, B4, B5, B6, B7, B8, B9};
    const int KLs[10] = {43, 43, 43, 43, 43, 21, 43, 43, 43, 43};
    const int NLs[10] = {43, 43, 43, 43, 21, 43, 43, 43, 43, 43};
#pragma unroll
    for (int L = 0; L < 10; ++L) {
      const float* Wl = Wp[L];
      const float* Bl = Bp[L];
      const int KL = KLs[L], NL = NLs[L];
      for (int idx = tid; idx < 48 * 64; idx += TPB) {
        int n = idx >> 6, kp = idx & 63;
        float v = 0.0f;
        if (n < NL) {
          int c = kp >> 5, g2 = (kp >> 3) & 3, j = kp & 7;
          int d = j >> 1, o = j & 1;
          int F;
          if (L == 0) F = kp;                               // natural
          else if (c == 0) F = 16 * (d >> 1) + 4 * g2 + 2 * (d & 1) + o;
          else if (d < 2)  F = 32 + 4 * g2 + 2 * d + o;     // t=2 half
          else             F = 63;                          // zero pad slot
          if (F < KL) v = Wl[F * NL + n];                   // W^T: W[F][n]
          else if (F == KL && L != 0) v = Bl[n];            // bias row
        }
        lw[L * WSLOT + n * WSTRIDE + kp] = (_Float16)v;
      }
    }
  }

  // layer-0 bias fragment (per-lane, matches C layout col = 16t+4g+r)
  float b0v[12];
#pragma unroll
  for (int t = 0; t < 3; ++t)
#pragma unroll
    for (int r = 0; r < 4; ++r) {
      int n = 16 * t + 4 * g + r;
      b0v[t * 4 + r] = (n < NCOL) ? B0[n] : 0.0f;
    }

  __syncthreads();  // weights ready; only barrier in the kernel

  const char* xc = (const char*)x;
  const unsigned blockbase = (unsigned)blockIdx.x * (ITERS * 512) + wave * 32;
  const unsigned LIM = (unsigned)(XBYTES - 4);

  float xv0[2][8], xv1[2][8];
  // prefetch iteration 0 (clamped tail reads give finite garbage, which is
  // annihilated by zero A rows at k>=43 — layer 0's k==43 row is zero)
#pragma unroll
  for (int s = 0; s < 2; ++s) {
    unsigned rb = (blockbase + 16 * s + lr) * ROWB;
#pragma unroll
    for (int j = 0; j < 8; ++j) {
      xv0[s][j] = *(const float*)(xc + (rb + 32u * g + 4u * j));
      unsigned a = rb + 128u + 32u * g + 4u * j;
      xv1[s][j] = *(const float*)(xc + (a < LIM ? a : LIM));
    }
  }

#pragma unroll 1
  for (int it = 0; it < ITERS; ++it) {
    const unsigned row0 = blockbase + (unsigned)it * 512u;

    // ---- layer-0 B-frags from prefetched registers (natural order) ----
    Frags B;
#pragma unroll
    for (int s = 0; s < 2; ++s) {
      union { unsigned d[4]; f16x8 v; } u0, u1;
#pragma unroll
      for (int j2 = 0; j2 < 4; ++j2) {
        u0.d[j2] = pk2(xv0[s][2 * j2], xv0[s][2 * j2 + 1]);
        u1.d[j2] = pk2(xv1[s][2 * j2], xv1[s][2 * j2 + 1]);
      }
      B.b[s][0] = u0.v;
      B.b[s][1] = u1.v;
    }

    // ---- prefetch next iteration's x ----
    if (it + 1 < ITERS) {
#pragma unroll
      for (int s = 0; s < 2; ++s) {
        unsigned rb = (row0 + 512u + 16 * s + lr) * ROWB;
#pragma unroll
        for (int j = 0; j < 8; ++j) {
          xv0[s][j] = *(const float*)(xc + (rb + 32u * g + 4u * j));
          unsigned a = rb + 128u + 32u * g + 4u * j;
          xv1[s][j] = *(const float*)(xc + (a < LIM ? a : LIM));
        }
      }
    }

    // ---- layers 0..8, hidden state entirely in registers ----
    B = layer_fwd<3, 2, true, 43, 2, true >(lw + 0 * WSLOT, B, b0v, g, lr);
    B = layer_fwd<3, 2, true, 43, 2, false>(lw + 1 * WSLOT, B, nullptr, g, lr);
    B = layer_fwd<3, 2, true, 43, 2, false>(lw + 2 * WSLOT, B, nullptr, g, lr);
    B = layer_fwd<3, 2, true, 43, 2, false>(lw + 3 * WSLOT, B, nullptr, g, lr);
    B = layer_fwd<2, 2, false, 21, 1, false>(lw + 4 * WSLOT, B, nullptr, g, lr);
    B = layer_fwd<3, 1, true, 43, 2, false>(lw + 5 * WSLOT, B, nullptr, g, lr);
    B = layer_fwd<3, 2, true, 43, 2, false>(lw + 6 * WSLOT, B, nullptr, g, lr);
    B = layer_fwd<3, 2, true, 43, 2, false>(lw + 7 * WSLOT, B, nullptr, g, lr);
    B = layer_fwd<3, 2, true, 43, 2, false>(lw + 8 * WSLOT, B, nullptr, g, lr);

    // ---- layer 9: linear, store fp32 to global ----
    {
      f32x4 a9[3][2];
#pragma unroll
      for (int t = 0; t < 3; ++t)
#pragma unroll
        for (int s = 0; s < 2; ++s) a9[t][s] = f32x4{0.f, 0.f, 0.f, 0.f};
#pragma unroll
      for (int c = 0; c < 2; ++c)
#pragma unroll
        for (int t = 0; t < 3; ++t) {
          f16x8 A = *(const f16x8*)(lw + 9 * WSLOT + (16 * t + lr) * WSTRIDE +
                                    8 * g + 32 * c);
#pragma unroll
          for (int s = 0; s < 2; ++s)
            a9[t][s] = __builtin_amdgcn_mfma_f32_16x16x32_f16(A, B.b[s][c],
                                                              a9[t][s], 0, 0, 0);
        }
#pragma unroll
      for (int t = 0; t < 3; ++t)
#pragma unroll
        for (int s = 0; s < 2; ++s)
#pragma unroll
          for (int r = 0; r < 4; ++r) {
            int col = 16 * t + 4 * g + r;
            if (col < NCOL)
              out[(size_t)(row0 + 16 * s + lr) * NCOL + col] = a9[t][s][r];
          }
    }
  }
}

extern "C" void kernel_launch(void* const* d_in, const int* in_sizes, int n_in,
                              void* d_out, int out_size, void* d_ws,
                              size_t ws_size, hipStream_t stream) {
  const float* x = (const float*)d_in[0];
  const float* W[10];
  const float* B[10];
  for (int i = 0; i < 10; ++i) {
    W[i] = (const float*)d_in[1 + 2 * i];
    B[i] = (const float*)d_in[2 + 2 * i];
  }
  (void)hipFuncSetAttribute(reinterpret_cast<const void*>(ae_kernel),
                            hipFuncAttributeMaxDynamicSharedMemorySize,
                            SMEM_BYTES);
  ae_kernel<<<dim3(NBLK), dim3(TPB), SMEM_BYTES, stream>>>(
      x, W[0], B[0], W[1], B[1], W[2], B[2], W[3], B[3], W[4], B[4],
      W[5], B[5], W[6], B[6], W[7], B[7], W[8], B[8], W[9], B[9],
      (float*)d_out);
}

// Round 6
// 460.590 us; speedup vs baseline: 1.1694x; 1.1694x over previous
//
#include <hip/hip_runtime.h>

// SensorAutoEncoder: 10-layer MLP over 1M rows of 43 floats, fused persistent
// kernel. fp16 MFMA (16x16x32) + fp32 accumulate. R6 = R5's math (D dwords
// reinterpreted directly as next layer's B-frag; induced k-permutation F
// folded into weight staging) with SSA-clean codegen: no array/pointer/ref
// params, no unions — struct-of-vectors by value + u32x4 bit_cast. All 10
// layers uniform (bias always via staged k-row; layer-0 multiplier 1.0 is
// injected into the x fragment at slot k=43).
//   B slot (c,g,j): c==0 -> F = 16*(j>>2) + 4g + (j&3)
//                   c==1, j<4 -> F = 32 + 4g + j ; else zero pad
// LDS holds only the fp16 (permuted) W^T tiles.

typedef __fp16 pk16x2 __attribute__((ext_vector_type(2)));   // cvt_pkrtz type
typedef _Float16 f16x8 __attribute__((ext_vector_type(8)));
typedef float f32x4 __attribute__((ext_vector_type(4)));
typedef unsigned u32x4 __attribute__((ext_vector_type(4)));

#define TPB 1024
#define NBLK 256
#define ITERS 8
#define NROWS 1048576
#define NCOL 43
#define ROWB 172u                       // bytes per x row (43 f32)
#define XBYTES (NROWS * (size_t)ROWB)   // 180,355,072 (< 2^31, u32 offsets ok)
#define WSTRIDE 72                      // halfwords per W^T row (144 B)
#define WSLOT (48 * WSTRIDE)            // halfwords per layer slot
#define SMEM_BYTES (10 * WSLOT * 2)     // 69120 B (weights only)

__device__ __forceinline__ float fast_tanh(float x) {
  // tanh(x) = 1 - 2/(1 + e^{2x});  e^{2x} = 2^{x * 2*log2(e)}
  float t = __builtin_amdgcn_exp2f(x * 2.8853900817779268f);
  float r = __builtin_amdgcn_rcpf(t + 1.0f);
  return __builtin_fmaf(-2.0f, r, 1.0f);
}

__device__ __forceinline__ unsigned pk2(float a, float b) {
  pk16x2 h = __builtin_amdgcn_cvt_pkrtz(a, b);
  return __builtin_bit_cast(unsigned, h);
}

struct FragsV { f16x8 s0c0, s0c1, s1c0, s1c1; };

// One layer, fully self-contained: MFMA vs LDS weights, epilogue
// (tanh + bias-column 1.0 forcing), pack straight into next B-frags.
template <int NT, int KC, bool DOTANH, int NLOUT, int KCN>
__device__ __forceinline__ FragsV layer_fwd(const _Float16* __restrict__ Wl,
                                            FragsV Bi, int g, int lr) {
  f16x8 Bv[2][2];
  Bv[0][0] = Bi.s0c0; Bv[0][1] = Bi.s0c1;
  Bv[1][0] = Bi.s1c0; Bv[1][1] = Bi.s1c1;

  f32x4 acc[3][2];
#pragma unroll
  for (int t = 0; t < NT; ++t)
#pragma unroll
    for (int s = 0; s < 2; ++s) acc[t][s] = f32x4{0.f, 0.f, 0.f, 0.f};

#pragma unroll
  for (int c = 0; c < KC; ++c)
#pragma unroll
    for (int t = 0; t < NT; ++t) {
      f16x8 A = *(const f16x8*)(Wl + (16 * t + lr) * WSTRIDE + 8 * g + 32 * c);
#pragma unroll
      for (int s = 0; s < 2; ++s)
        acc[t][s] = __builtin_amdgcn_mfma_f32_16x16x32_f16(A, Bv[s][c],
                                                           acc[t][s], 0, 0, 0);
    }

  f16x8 oc0[2], oc1[2];
#pragma unroll
  for (int s = 0; s < 2; ++s) {
    unsigned pk[3][2];
#pragma unroll
    for (int t = 0; t < NT; ++t) {
      float v[4];
#pragma unroll
      for (int r = 0; r < 4; ++r) {
        float u = acc[t][s][r];
        if (DOTANH) u = fast_tanh(u);
        if (t == (NLOUT >> 4)) {                 // bias-mult column -> 1.0
          int col = 16 * t + 4 * g + r;
          u = (col == NLOUT) ? 1.0f : u;
        }
        v[r] = u;
      }
      pk[t][0] = pk2(v[0], v[1]);
      pk[t][1] = pk2(v[2], v[3]);
    }
    u32x4 d0 = {pk[0][0], pk[0][1], pk[1][0], pk[1][1]};
    oc0[s] = __builtin_bit_cast(f16x8, d0);
    if (KCN == 2) {
      u32x4 d1 = {pk[NT - 1][0], pk[NT - 1][1], 0u, 0u};
      oc1[s] = __builtin_bit_cast(f16x8, d1);
    } else {
      oc1[s] = oc0[s];   // unused by a KC=1 consumer
    }
  }
  FragsV O;
  O.s0c0 = oc0[0]; O.s0c1 = oc1[0];
  O.s1c0 = oc0[1]; O.s1c1 = oc1[1];
  return O;
}

extern "C" __global__ void __launch_bounds__(TPB, 4)
ae_kernel(const float* __restrict__ x,
          const float* __restrict__ W0, const float* __restrict__ B0,
          const float* __restrict__ W1, const float* __restrict__ B1,
          const float* __restrict__ W2, const float* __restrict__ B2,
          const float* __restrict__ W3, const float* __restrict__ B3,
          const float* __restrict__ W4, const float* __restrict__ B4,
          const float* __restrict__ W5, const float* __restrict__ B5,
          const float* __restrict__ W6, const float* __restrict__ B6,
          const float* __restrict__ W7, const float* __restrict__ B7,
          const float* __restrict__ W8, const float* __restrict__ B8,
          const float* __restrict__ W9, const float* __restrict__ B9,
          float* __restrict__ out) {
  extern __shared__ char smem[];
  _Float16* lw = (_Float16*)smem;

  const int tid = threadIdx.x;
  const int wave = tid >> 6;
  const int lane = tid & 63;
  const int g = lane >> 4;
  const int lr = lane & 15;

  // ---- stage weights as fp16 W^T (k-permutation F for layers 1..9), bias
  //      at the slot mapping to k==KL; everything uniform across layers ----
  {
    const float* Wp[10] = {W0, W1, W2, W3, W4, W5, W6, W7, W8, W9};
    const float* Bp[10] = {B0, B1, B2, B3, B4, B5, B6, B7, B8, B9};
    const int KLs[10] = {43, 43, 43, 43, 43, 21, 43, 43, 43, 43};
    const int NLs[10] = {43, 43, 43, 43, 21, 43, 43, 43, 43, 43};
#pragma unroll
    for (int L = 0; L < 10; ++L) {
      const float* Wl = Wp[L];
      const float* Bl = Bp[L];
      const int KL = KLs[L], NL = NLs[L];
      for (int idx = tid; idx < 48 * 64; idx += TPB) {
        int n = idx >> 6, kp = idx & 63;
        float v = 0.0f;
        if (n < NL) {
          int c = kp >> 5, g2 = (kp >> 3) & 3, j = kp & 7;
          int F;
          if (L == 0) F = kp;                               // natural
          else if (c == 0) F = 16 * (j >> 2) + 4 * g2 + (j & 3);
          else if (j < 4)  F = 32 + 4 * g2 + j;             // t=2 half
          else             F = 63;                          // zero pad slot
          if (F < KL) v = Wl[F * NL + n];                   // W^T: W[F][n]
          else if (F == KL) v = Bl[n];                      // bias row
        }
        lw[L * WSLOT + n * WSTRIDE + kp] = (_Float16)v;
      }
    }
  }

  __syncthreads();  // weights ready; only barrier in the kernel

  const char* xc = (const char*)x;
  const unsigned blockbase = (unsigned)blockIdx.x * (ITERS * 512) + wave * 32;
  const unsigned LIM = (unsigned)(XBYTES - 4);

  float xv0[2][8], xv1[2][8];
  // prefetch iteration 0 (clamped tail reads give finite garbage, which is
  // annihilated by zero A rows at k>43; slot k==43 is overwritten with 1.0)
#pragma unroll
  for (int s = 0; s < 2; ++s) {
    unsigned rb = (blockbase + 16 * s + lr) * ROWB;
#pragma unroll
    for (int j = 0; j < 8; ++j) {
      xv0[s][j] = *(const float*)(xc + (rb + 32u * g + 4u * j));
      unsigned a = rb + 128u + 32u * g + 4u * j;
      xv1[s][j] = *(const float*)(xc + (a < LIM ? a : LIM));
    }
  }

#pragma unroll 1
  for (int it = 0; it < ITERS; ++it) {
    const unsigned row0 = blockbase + (unsigned)it * 512u;

    // ---- layer-0 B-frags from prefetched registers (natural order);
    //      k==43 slot (c=1,g=1,j=3) := 1.0 — the bias-row multiplier ----
    FragsV B;
#pragma unroll
    for (int s = 0; s < 2; ++s) {
      float e3 = (g == 1) ? 1.0f : xv1[s][3];
      u32x4 d0 = {pk2(xv0[s][0], xv0[s][1]), pk2(xv0[s][2], xv0[s][3]),
                  pk2(xv0[s][4], xv0[s][5]), pk2(xv0[s][6], xv0[s][7])};
      u32x4 d1 = {pk2(xv1[s][0], xv1[s][1]), pk2(xv1[s][2], e3),
                  pk2(xv1[s][4], xv1[s][5]), pk2(xv1[s][6], xv1[s][7])};
      if (s == 0) { B.s0c0 = __builtin_bit_cast(f16x8, d0);
                    B.s0c1 = __builtin_bit_cast(f16x8, d1); }
      else        { B.s1c0 = __builtin_bit_cast(f16x8, d0);
                    B.s1c1 = __builtin_bit_cast(f16x8, d1); }
    }

    // ---- prefetch next iteration's x ----
    if (it + 1 < ITERS) {
#pragma unroll
      for (int s = 0; s < 2; ++s) {
        unsigned rb = (row0 + 512u + 16 * s + lr) * ROWB;
#pragma unroll
        for (int j = 0; j < 8; ++j) {
          xv0[s][j] = *(const float*)(xc + (rb + 32u * g + 4u * j));
          unsigned a = rb + 128u + 32u * g + 4u * j;
          xv1[s][j] = *(const float*)(xc + (a < LIM ? a : LIM));
        }
      }
    }

    // ---- layers 0..8, hidden state entirely in registers ----
    B = layer_fwd<3, 2, true, 43, 2>(lw + 0 * WSLOT, B, g, lr);
    B = layer_fwd<3, 2, true, 43, 2>(lw + 1 * WSLOT, B, g, lr);
    B = layer_fwd<3, 2, true, 43, 2>(lw + 2 * WSLOT, B, g, lr);
    B = layer_fwd<3, 2, true, 43, 2>(lw + 3 * WSLOT, B, g, lr);
    B = layer_fwd<2, 2, false, 21, 1>(lw + 4 * WSLOT, B, g, lr);
    B = layer_fwd<3, 1, true, 43, 2>(lw + 5 * WSLOT, B, g, lr);
    B = layer_fwd<3, 2, true, 43, 2>(lw + 6 * WSLOT, B, g, lr);
    B = layer_fwd<3, 2, true, 43, 2>(lw + 7 * WSLOT, B, g, lr);
    B = layer_fwd<3, 2, true, 43, 2>(lw + 8 * WSLOT, B, g, lr);

    // ---- layer 9: linear, store fp32 to global ----
    {
      f16x8 Bv[2][2];
      Bv[0][0] = B.s0c0; Bv[0][1] = B.s0c1;
      Bv[1][0] = B.s1c0; Bv[1][1] = B.s1c1;
      f32x4 a9[3][2];
#pragma unroll
      for (int t = 0; t < 3; ++t)
#pragma unroll
        for (int s = 0; s < 2; ++s) a9[t][s] = f32x4{0.f, 0.f, 0.f, 0.f};
#pragma unroll
      for (int c = 0; c < 2; ++c)
#pragma unroll
        for (int t = 0; t < 3; ++t) {
          f16x8 A = *(const f16x8*)(lw + 9 * WSLOT + (16 * t + lr) * WSTRIDE +
                                    8 * g + 32 * c);
#pragma unroll
          for (int s = 0; s < 2; ++s)
            a9[t][s] = __builtin_amdgcn_mfma_f32_16x16x32_f16(A, Bv[s][c],
                                                              a9[t][s], 0, 0, 0);
        }
#pragma unroll
      for (int t = 0; t < 3; ++t)
#pragma unroll
        for (int s = 0; s < 2; ++s)
#pragma unroll
          for (int r = 0; r < 4; ++r) {
            int col = 16 * t + 4 * g + r;
            if (col < NCOL)
              out[(size_t)(row0 + 16 * s + lr) * NCOL + col] = a9[t][s][r];
          }
    }
  }
}

extern "C" void kernel_launch(void* const* d_in, const int* in_sizes, int n_in,
                              void* d_out, int out_size, void* d_ws,
                              size_t ws_size, hipStream_t stream) {
  const float* x = (const float*)d_in[0];
  const float* W[10];
  const float* B[10];
  for (int i = 0; i < 10; ++i) {
    W[i] = (const float*)d_in[1 + 2 * i];
    B[i] = (const float*)d_in[2 + 2 * i];
  }
  (void)hipFuncSetAttribute(reinterpret_cast<const void*>(ae_kernel),
                            hipFuncAttributeMaxDynamicSharedMemorySize,
                            SMEM_BYTES);
  ae_kernel<<<dim3(NBLK), dim3(TPB), SMEM_BYTES, stream>>>(
      x, W[0], B[0], W[1], B[1], W[2], B[2], W[3], B[3], W[4], B[4],
      W[5], B[5], W[6], B[6], W[7], B[7], W[8], B[8], W[9], B[9],
      (float*)d_out);
}

// Round 7
// 137.275 us; speedup vs baseline: 3.9235x; 3.3552x over previous
//
#include <hip/hip_runtime.h>

// SensorAutoEncoder: 10-layer MLP over 1M rows of 43 floats, fused persistent
// kernel. fp16 MFMA (16x16x32) + fp32 accumulate. R7 = R6's register-resident
// layer chain (D dwords reinterpreted as next B-frag, k-permutation F folded
// into weight staging) + R1's global_load_lds x-staging, so per-thread live
// state fits the backend's observed 64-VGPR target (no scratch).
//   B slot (c,g,j): c==0 -> F = 16*(j>>2) + 4g + (j&3)
//                   c==1, j<4 -> F = 32 + 4g + j ; else zero pad
// Weight slots are 44 rows; A-reads at rows 44..47 spill into the next slot's
// first rows — harmless: those outputs are bounded (tanh) or exact 0, and the
// consumer's A slots for them are staged 0 (F=44+j>43), annihilating them.

typedef __fp16 pk16x2 __attribute__((ext_vector_type(2)));   // cvt_pkrtz type
typedef _Float16 f16x8 __attribute__((ext_vector_type(8)));
typedef float f32x4 __attribute__((ext_vector_type(4)));
typedef unsigned u32x4 __attribute__((ext_vector_type(4)));

#define TPB 1024
#define NBLK 256
#define ITERS 8
#define NROWS 1048576
#define NCOL 43
#define ROWB 172u                        // bytes per x row (43 f32)
#define XBYTES ((size_t)NROWS * ROWB)    // 180,355,072
#define WSTRIDE 72                       // halfwords per W^T row (144 B)
#define SLOT_ROWS 44
#define WSLOT (SLOT_ROWS * WSTRIDE)      // 3168 halfwords per layer slot
#define W_BYTES (10 * WSLOT * 2)         // 63360 B
#define XBUF_BYTES 6144                  // 32 rows * 172 B = 5504, pad to 6 KiB
#define X_BASE W_BYTES
#define SMEM_BYTES (X_BASE + 16 * XBUF_BYTES)  // 161664 <= 163840

__device__ __forceinline__ float fast_tanh(float x) {
  // tanh(x) = 1 - 2/(1 + e^{2x});  e^{2x} = 2^{x * 2*log2(e)}
  float t = __builtin_amdgcn_exp2f(x * 2.8853900817779268f);
  float r = __builtin_amdgcn_rcpf(t + 1.0f);
  return __builtin_fmaf(-2.0f, r, 1.0f);
}

__device__ __forceinline__ unsigned pk2(float a, float b) {
  pk16x2 h = __builtin_amdgcn_cvt_pkrtz(a, b);
  return __builtin_bit_cast(unsigned, h);
}

// Async global->LDS DMA of one 32-row x tile (6 x 1KiB chunks, 16B/lane).
// Per-lane global src (clamped in-bounds); wave-uniform LDS base.
__device__ __forceinline__ void issue_dma(const char* xc, const char* xlim,
                                          char* xb, unsigned rowbytes,
                                          int lane) {
  const char* base = xc + rowbytes;
#pragma unroll
  for (int c = 0; c < 6; ++c) {
    const char* src = base + c * 1024 + lane * 16;
    src = (src > xlim) ? xlim : src;
    __builtin_amdgcn_global_load_lds(
        (const __attribute__((address_space(1))) void*)src,
        (__attribute__((address_space(3))) void*)(xb + c * 1024), 16, 0, 0);
  }
}

struct FragsV { f16x8 s0c0, s0c1, s1c0, s1c1; };

// One layer, self-contained: MFMA vs LDS weights, epilogue (tanh +
// bias-column 1.0 forcing), pack straight into next B-frags.
template <int NT, int KC, bool DOTANH, int NLOUT, int KCN>
__device__ __forceinline__ FragsV layer_fwd(const _Float16* __restrict__ Wl,
                                            FragsV Bi, int g, int lr) {
  f16x8 Bv[2][2];
  Bv[0][0] = Bi.s0c0; Bv[0][1] = Bi.s0c1;
  Bv[1][0] = Bi.s1c0; Bv[1][1] = Bi.s1c1;

  f32x4 acc[3][2];
#pragma unroll
  for (int t = 0; t < NT; ++t)
#pragma unroll
    for (int s = 0; s < 2; ++s) acc[t][s] = f32x4{0.f, 0.f, 0.f, 0.f};

#pragma unroll
  for (int c = 0; c < KC; ++c)
#pragma unroll
    for (int t = 0; t < NT; ++t) {
      f16x8 A = *(const f16x8*)(Wl + (16 * t + lr) * WSTRIDE + 8 * g + 32 * c);
#pragma unroll
      for (int s = 0; s < 2; ++s)
        acc[t][s] = __builtin_amdgcn_mfma_f32_16x16x32_f16(A, Bv[s][c],
                                                           acc[t][s], 0, 0, 0);
    }

  f16x8 oc0[2], oc1[2];
#pragma unroll
  for (int s = 0; s < 2; ++s) {
    unsigned pk[3][2];
#pragma unroll
    for (int t = 0; t < NT; ++t) {
      float v[4];
#pragma unroll
      for (int r = 0; r < 4; ++r) {
        float u = acc[t][s][r];
        if (DOTANH) u = fast_tanh(u);
        if (t == (NLOUT >> 4)) {                 // bias-mult column -> 1.0
          int col = 16 * t + 4 * g + r;
          u = (col == NLOUT) ? 1.0f : u;
        }
        v[r] = u;
      }
      pk[t][0] = pk2(v[0], v[1]);
      pk[t][1] = pk2(v[2], v[3]);
    }
    u32x4 d0 = {pk[0][0], pk[0][1], pk[1][0], pk[1][1]};
    oc0[s] = __builtin_bit_cast(f16x8, d0);
    if (KCN == 2) {
      u32x4 d1 = {pk[NT - 1][0], pk[NT - 1][1], 0u, 0u};
      oc1[s] = __builtin_bit_cast(f16x8, d1);
    } else {
      oc1[s] = oc0[s];   // unused by a KC=1 consumer
    }
  }
  FragsV O;
  O.s0c0 = oc0[0]; O.s0c1 = oc1[0];
  O.s1c0 = oc0[1]; O.s1c1 = oc1[1];
  return O;
}

extern "C" __global__ void __launch_bounds__(TPB)
ae_kernel(const float* __restrict__ x,
          const float* __restrict__ W0, const float* __restrict__ B0,
          const float* __restrict__ W1, const float* __restrict__ B1,
          const float* __restrict__ W2, const float* __restrict__ B2,
          const float* __restrict__ W3, const float* __restrict__ B3,
          const float* __restrict__ W4, const float* __restrict__ B4,
          const float* __restrict__ W5, const float* __restrict__ B5,
          const float* __restrict__ W6, const float* __restrict__ B6,
          const float* __restrict__ W7, const float* __restrict__ B7,
          const float* __restrict__ W8, const float* __restrict__ B8,
          const float* __restrict__ W9, const float* __restrict__ B9,
          float* __restrict__ out) {
  extern __shared__ char smem[];
  _Float16* lw = (_Float16*)smem;

  const int tid = threadIdx.x;
  const int wave = tid >> 6;
  const int lane = tid & 63;
  const int g = lane >> 4;
  const int lr = lane & 15;

  // ---- stage weights as fp16 W^T (k-permutation F for layers 1..9), bias
  //      at the slot mapping to k==KL; 44 rows per slot ----
  {
    const float* Wp[10] = {W0, W1, W2, W3, W4, W5, W6, W7, W8, W9};
    const float* Bp[10] = {B0, B1, B2, B3, B4, B5, B6, B7, B8, B9};
    const int KLs[10] = {43, 43, 43, 43, 43, 21, 43, 43, 43, 43};
    const int NLs[10] = {43, 43, 43, 43, 21, 43, 43, 43, 43, 43};
#pragma unroll
    for (int L = 0; L < 10; ++L) {
      const float* Wl = Wp[L];
      const float* Bl = Bp[L];
      const int KL = KLs[L], NL = NLs[L];
      for (int idx = tid; idx < SLOT_ROWS * 64; idx += TPB) {
        int n = idx >> 6, kp = idx & 63;
        float v = 0.0f;
        if (n < NL) {
          int c = kp >> 5, g2 = (kp >> 3) & 3, j = kp & 7;
          int F;
          if (L == 0) F = kp;                               // natural
          else if (c == 0) F = 16 * (j >> 2) + 4 * g2 + (j & 3);
          else if (j < 4)  F = 32 + 4 * g2 + j;             // t=2 half
          else             F = 63;                          // zero pad slot
          if (F < KL) v = Wl[F * NL + n];                   // W^T: W[F][n]
          else if (F == KL) v = Bl[n];                      // bias row
        }
        lw[L * WSLOT + n * WSTRIDE + kp] = (_Float16)v;
      }
    }
  }

  __syncthreads();  // weights ready; only barrier in the kernel

  const char* xc = (const char*)x;
  const char* xlim = xc + (XBYTES - 16);
  const unsigned blockbase = (unsigned)blockIdx.x * (ITERS * 512) + wave * 32;
  float* xb = (float*)(smem + X_BASE + wave * XBUF_BYTES);

  issue_dma(xc, xlim, (char*)xb, blockbase * ROWB, lane);

#pragma unroll 1
  for (int it = 0; it < ITERS; ++it) {
    const unsigned row0 = blockbase + (unsigned)it * 512u;

    asm volatile("s_waitcnt vmcnt(0)" ::: "memory");  // x tile landed in LDS

    // ---- layer-0 B-frags from LDS (natural k order); slot k==43
    //      (c=1,g=1,j=3) := 1.0 — the bias-row multiplier ----
    FragsV B;
#pragma unroll
    for (int s = 0; s < 2; ++s) {
      const float* xr = xb + (16 * s + lr) * NCOL;
      float f0[8], f1[8];
#pragma unroll
      for (int j = 0; j < 8; ++j) {
        f0[j] = xr[8 * g + j];          // c=0: k = 8g+j
        f1[j] = xr[32 + 8 * g + j];     // c=1: k = 32+8g+j (tail reads junk,
      }                                 //      annihilated by zero A rows)
      float e3 = (g == 1) ? 1.0f : f1[3];
      u32x4 d0 = {pk2(f0[0], f0[1]), pk2(f0[2], f0[3]),
                  pk2(f0[4], f0[5]), pk2(f0[6], f0[7])};
      u32x4 d1 = {pk2(f1[0], f1[1]), pk2(f1[2], e3),
                  pk2(f1[4], f1[5]), pk2(f1[6], f1[7])};
      if (s == 0) { B.s0c0 = __builtin_bit_cast(f16x8, d0);
                    B.s0c1 = __builtin_bit_cast(f16x8, d1); }
      else        { B.s1c0 = __builtin_bit_cast(f16x8, d0);
                    B.s1c1 = __builtin_bit_cast(f16x8, d1); }
    }

    // frag reads complete -> safe to overwrite the buffer with next tile
    asm volatile("s_waitcnt lgkmcnt(0)" ::: "memory");
    if (it + 1 < ITERS)
      issue_dma(xc, xlim, (char*)xb, (row0 + 512u) * ROWB, lane);

    // ---- layers 0..8, hidden state entirely in registers ----
    B = layer_fwd<3, 2, true, 43, 2>(lw + 0 * WSLOT, B, g, lr);
    B = layer_fwd<3, 2, true, 43, 2>(lw + 1 * WSLOT, B, g, lr);
    B = layer_fwd<3, 2, true, 43, 2>(lw + 2 * WSLOT, B, g, lr);
    B = layer_fwd<3, 2, true, 43, 2>(lw + 3 * WSLOT, B, g, lr);
    B = layer_fwd<2, 2, false, 21, 1>(lw + 4 * WSLOT, B, g, lr);
    B = layer_fwd<3, 1, true, 43, 2>(lw + 5 * WSLOT, B, g, lr);
    B = layer_fwd<3, 2, true, 43, 2>(lw + 6 * WSLOT, B, g, lr);
    B = layer_fwd<3, 2, true, 43, 2>(lw + 7 * WSLOT, B, g, lr);
    B = layer_fwd<3, 2, true, 43, 2>(lw + 8 * WSLOT, B, g, lr);

    // ---- layer 9: linear, store fp32 to global ----
    {
      f16x8 Bv[2][2];
      Bv[0][0] = B.s0c0; Bv[0][1] = B.s0c1;
      Bv[1][0] = B.s1c0; Bv[1][1] = B.s1c1;
      f32x4 a9[3][2];
#pragma unroll
      for (int t = 0; t < 3; ++t)
#pragma unroll
        for (int s = 0; s < 2; ++s) a9[t][s] = f32x4{0.f, 0.f, 0.f, 0.f};
#pragma unroll
      for (int c = 0; c < 2; ++c)
#pragma unroll
        for (int t = 0; t < 3; ++t) {
          f16x8 A = *(const f16x8*)(lw + 9 * WSLOT + (16 * t + lr) * WSTRIDE +
                                    8 * g + 32 * c);
#pragma unroll
          for (int s = 0; s < 2; ++s)
            a9[t][s] = __builtin_amdgcn_mfma_f32_16x16x32_f16(A, Bv[s][c],
                                                              a9[t][s], 0, 0, 0);
        }
#pragma unroll
      for (int t = 0; t < 3; ++t)
#pragma unroll
        for (int s = 0; s < 2; ++s)
#pragma unroll
          for (int r = 0; r < 4; ++r) {
            int col = 16 * t + 4 * g + r;
            if (col < NCOL)
              out[(size_t)(row0 + 16 * s + lr) * NCOL + col] = a9[t][s][r];
          }
    }
  }
}

extern "C" void kernel_launch(void* const* d_in, const int* in_sizes, int n_in,
                              void* d_out, int out_size, void* d_ws,
                              size_t ws_size, hipStream_t stream) {
  const float* x = (const float*)d_in[0];
  const float* W[10];
  const float* B[10];
  for (int i = 0; i < 10; ++i) {
    W[i] = (const float*)d_in[1 + 2 * i];
    B[i] = (const float*)d_in[2 + 2 * i];
  }
  (void)hipFuncSetAttribute(reinterpret_cast<const void*>(ae_kernel),
                            hipFuncAttributeMaxDynamicSharedMemorySize,
                            SMEM_BYTES);
  ae_kernel<<<dim3(NBLK), dim3(TPB), SMEM_BYTES, stream>>>(
      x, W[0], B[0], W[1], B[1], W[2], B[2], W[3], B[3], W[4], B[4],
      W[5], B[5], W[6], B[6], W[7], B[7], W[8], B[8], W[9], B[9],
      (float*)d_out);
}